// Round 16
// baseline (783.731 us; speedup 1.0000x reference)
//
#include <hip/hip_runtime.h>
#include <stdint.h>

#define MROWS 131072                     // 2048 windows * 64 tokens
#define LOG2E 1.44269504088896340736f
#define QSCALE 0.17677669529663688110f   // 32^-0.5

typedef _Float16 f16x8 __attribute__((ext_vector_type(8)));
typedef float f32x4 __attribute__((ext_vector_type(4)));
typedef unsigned short u16;
typedef u16 u16x4 __attribute__((ext_vector_type(4)));
typedef u16 u16x8 __attribute__((ext_vector_type(8)));

#define GLD16(gp, lp) __builtin_amdgcn_global_load_lds( \
    (const __attribute__((address_space(1))) void*)(gp), \
    (__attribute__((address_space(3))) void*)(lp), 16, 0, 0)

static __device__ __forceinline__ u16 f2h(float f) {
    _Float16 h = (_Float16)f;             // RNE
    return __builtin_bit_cast(unsigned short, h);
}
static __device__ __forceinline__ float shflx(float v, int m) {
    return __shfl_xor(v, m, 64);
}
// bijective XCD swizzle: 4096 wgs, 8 XCDs, 512-wg contiguous chunk per XCD
static __device__ __forceinline__ int swz4096(int bid) {
    return (bid & 7) * 512 + (bid >> 3);
}

// ---------------- setup kernels ----------------
// all four weight transposes in one launch: grid (1024, 4)
__global__ void wt_all(const float* __restrict__ Wq, const float* __restrict__ Wkv,
                       const float* __restrict__ Wp,
                       u16* __restrict__ wqT, u16* __restrict__ wkvKT,
                       u16* __restrict__ wkvVT, u16* __restrict__ wprT) {
    int idx = blockIdx.x * 256 + threadIdx.x;
    int n = idx >> 9, k = idx & 511;
    switch (blockIdx.y) {
        case 0: wqT[idx]   = f2h(Wq[(size_t)k * 512 + n]); break;
        case 1: wkvKT[idx] = f2h(Wkv[(size_t)k * 1024 + n]); break;
        case 2: wkvVT[idx] = f2h(Wkv[(size_t)k * 1024 + 512 + n]); break;
        default: wprT[idx] = f2h(Wp[(size_t)k * 512 + n]); break;
    }
}
// combined (rel-pos bias + shift mask), stored TRANSPOSED: cmb[wmod][h][j][i]
__global__ void cmb_pre(const float* __restrict__ table, const float* __restrict__ mask,
                        float* __restrict__ cmb) {
    int wmod = blockIdx.x, h = blockIdx.y;
    float* outp = cmb + (((size_t)wmod * 16 + h) << 12);
    const float* mp = mask + ((size_t)wmod << 12);
    for (int e = threadIdx.x; e < 4096; e += 256) {
        int j = e >> 6, i = e & 63;
        int idx = ((i >> 3) - (j >> 3) + 7) * 15 + ((i & 7) - (j & 7) + 7);
        outp[e] = table[idx * 16 + h] + mp[i * 64 + j];
    }
}

// ---------------- Q/K GEMM: BK=32; A staged as RAW fp32 via global_load_lds
// (XOR-swizzled 16B blocks within each 128B row, pre-swizzled global source,
//  linear LDS dest), fp32->fp16 cvt on the LDS->fragment read path (overlaps
//  MFMA); B fp16 via global_load_lds as before.
__global__ __launch_bounds__(256, 4) void gemm_qk(
    const float* __restrict__ A, const u16* __restrict__ BT,
    const float* __restrict__ bias, u16* __restrict__ outp, float scale)
{
    __shared__ float Af[128 * 32];     // 16 KB, linear (gld_lds dest)
    __shared__ u16 Bs[128 * 32];       // 8 KB
    const int tid = threadIdx.x;
    const int l = tid & 63, w = tid >> 6;
    const int al = l & 15, g = l >> 4;
    const int wr = w >> 1, wc = w & 1;
    const int wg = swz4096(blockIdx.x);
    const int n0 = (wg & 3) * 128, m0 = (wg >> 2) * 128;
    const int srow = tid >> 2, sc8 = (tid & 3) * 8;
    f32x4 acc[4][4] = {};

    for (int kk = 0; kk < 512; kk += 32) {
        #pragma unroll
        for (int r = 0; r < 2; ++r) {
            int row = r * 64 + srow;
            GLD16(BT + (size_t)(n0 + row) * 512 + kk + sc8, &Bs[row * 32 + sc8]);
        }
        #pragma unroll
        for (int i = 0; i < 4; ++i) {
            int byte = w * 4096 + i * 1024 + l * 16;
            int row  = byte >> 7;            // 128 B per fp32 row
            int blk  = (byte >> 4) & 7;      // 16B block within row
            int gblk = blk ^ (row & 7);      // pre-swizzled SOURCE block
            GLD16(A + (size_t)(m0 + row) * 512 + kk + gblk * 4,
                  (char*)Af + byte);
        }
        __syncthreads();
        {
            f16x8 af[4], bfr[4];
            #pragma unroll
            for (int mt = 0; mt < 4; ++mt) {
                int row = wr*64 + mt*16 + al;
                int b0 = ((2*g) ^ (row & 7)) * 4;          // word idx of lo block
                f32x4 lo = *(const f32x4*)&Af[row*32 + b0];
                f32x4 hi = *(const f32x4*)&Af[row*32 + (b0 ^ 4)];
                f16x8 v;
                v[0]=(_Float16)lo[0]; v[1]=(_Float16)lo[1];
                v[2]=(_Float16)lo[2]; v[3]=(_Float16)lo[3];
                v[4]=(_Float16)hi[0]; v[5]=(_Float16)hi[1];
                v[6]=(_Float16)hi[2]; v[7]=(_Float16)hi[3];
                af[mt] = v;
            }
            #pragma unroll
            for (int nt = 0; nt < 4; ++nt)
                bfr[nt] = *(const f16x8*)&Bs[(wc*64 + nt*16 + al) * 32 + g*8];
            #pragma unroll
            for (int mt = 0; mt < 4; ++mt)
                #pragma unroll
                for (int nt = 0; nt < 4; ++nt)
                    acc[mt][nt] = __builtin_amdgcn_mfma_f32_16x16x32_f16(af[mt], bfr[nt], acc[mt][nt], 0, 0, 0);
        }
        __syncthreads();
    }
    #pragma unroll
    for (int nt = 0; nt < 4; ++nt) {
        int col = n0 + wc*64 + nt*16 + al;
        float bv = bias[col];
        #pragma unroll
        for (int mt = 0; mt < 4; ++mt)
            #pragma unroll
            for (int rg = 0; rg < 4; ++rg) {
                size_t row = (size_t)(m0 + wr*64 + mt*16 + g*4 + rg);
                outp[row * 512 + col] = f2h((acc[mt][nt][rg] + bv) * scale);
            }
    }
}

// ---------------- V GEMM: same fp32-in-LDS A path; V^T epilogue [win][h][d][k]
__global__ __launch_bounds__(256, 4) void gemm_v(
    const float* __restrict__ A, const u16* __restrict__ BT,
    const float* __restrict__ bias, u16* __restrict__ outp)
{
    __shared__ float Af[128 * 32];
    __shared__ u16 Bs[128 * 32];
    const int tid = threadIdx.x;
    const int l = tid & 63, w = tid >> 6;
    const int al = l & 15, g = l >> 4;
    const int wr = w >> 1, wc = w & 1;
    const int wg = swz4096(blockIdx.x);
    const int n0 = (wg & 3) * 128, m0 = (wg >> 2) * 128;
    const int srow = tid >> 2, sc8 = (tid & 3) * 8;
    f32x4 acc[4][4] = {};

    for (int kk = 0; kk < 512; kk += 32) {
        #pragma unroll
        for (int r = 0; r < 2; ++r) {
            int row = r * 64 + srow;
            GLD16(BT + (size_t)(n0 + row) * 512 + kk + sc8, &Bs[row * 32 + sc8]);
        }
        #pragma unroll
        for (int i = 0; i < 4; ++i) {
            int byte = w * 4096 + i * 1024 + l * 16;
            int row  = byte >> 7;
            int blk  = (byte >> 4) & 7;
            int gblk = blk ^ (row & 7);
            GLD16(A + (size_t)(m0 + row) * 512 + kk + gblk * 4,
                  (char*)Af + byte);
        }
        __syncthreads();
        {
            f16x8 af[4], bfr[4];
            #pragma unroll
            for (int mt = 0; mt < 4; ++mt) {
                int row = wr*64 + mt*16 + al;
                int b0 = ((2*g) ^ (row & 7)) * 4;
                f32x4 lo = *(const f32x4*)&Af[row*32 + b0];
                f32x4 hi = *(const f32x4*)&Af[row*32 + (b0 ^ 4)];
                f16x8 v;
                v[0]=(_Float16)lo[0]; v[1]=(_Float16)lo[1];
                v[2]=(_Float16)lo[2]; v[3]=(_Float16)lo[3];
                v[4]=(_Float16)hi[0]; v[5]=(_Float16)hi[1];
                v[6]=(_Float16)hi[2]; v[7]=(_Float16)hi[3];
                af[mt] = v;
            }
            #pragma unroll
            for (int nt = 0; nt < 4; ++nt)
                bfr[nt] = *(const f16x8*)&Bs[(wc*64 + nt*16 + al) * 32 + g*8];
            #pragma unroll
            for (int mt = 0; mt < 4; ++mt)
                #pragma unroll
                for (int nt = 0; nt < 4; ++nt)
                    acc[mt][nt] = __builtin_amdgcn_mfma_f32_16x16x32_f16(af[mt], bfr[nt], acc[mt][nt], 0, 0, 0);
        }
        __syncthreads();
    }
    #pragma unroll
    for (int nt = 0; nt < 4; ++nt) {
        int col = n0 + wc*64 + nt*16 + al;
        int hh_ = col >> 5, d = col & 31;
        float bv = bias[col];
        #pragma unroll
        for (int mt = 0; mt < 4; ++mt) {
            int row0 = m0 + wr*64 + mt*16 + g*4;
            int window = row0 >> 6, k0 = row0 & 63;
            size_t off = ((size_t)window << 15) + (hh_ << 11) + (d << 6) + k0;
            u16x4 hv;
            #pragma unroll
            for (int rg = 0; rg < 4; ++rg)
                hv[rg] = f2h(acc[mt][nt][rg] + bv);
            *(u16x4*)(outp + off) = hv;
        }
    }
}

// ---------------- proj GEMM: BK=32, A (fp16 O) + B via global_load_lds, fp32 out
__global__ __launch_bounds__(256, 4) void gemm_proj(
    const u16* __restrict__ A1, const u16* __restrict__ BT,
    const float* __restrict__ bias, float* __restrict__ outp)
{
    __shared__ u16 As[128*32], Bs[128*32];
    const int tid = threadIdx.x;
    const int l = tid & 63, w = tid >> 6;
    const int al = l & 15, g = l >> 4;
    const int wr = w >> 1, wc = w & 1;
    const int wg = swz4096(blockIdx.x);
    const int n0 = (wg & 3) * 128, m0 = (wg >> 2) * 128;
    const int srow = tid >> 2, sc8 = (tid & 3) * 8;
    f32x4 acc[4][4] = {};

    for (int kk = 0; kk < 512; kk += 32) {
        #pragma unroll
        for (int r = 0; r < 2; ++r) {
            int row = r * 64 + srow;
            size_t aoff = (size_t)(m0 + row) * 512 + kk + sc8;
            size_t boff = (size_t)(n0 + row) * 512 + kk + sc8;
            int loff = row * 32 + sc8;
            GLD16(A1 + aoff, &As[loff]);
            GLD16(BT + boff, &Bs[loff]);
        }
        __syncthreads();
        {
            f16x8 af[4], bfr[4];
            #pragma unroll
            for (int mt = 0; mt < 4; ++mt)
                af[mt] = *(const f16x8*)&As[(wr*64 + mt*16 + al) * 32 + g*8];
            #pragma unroll
            for (int nt = 0; nt < 4; ++nt)
                bfr[nt] = *(const f16x8*)&Bs[(wc*64 + nt*16 + al) * 32 + g*8];
            #pragma unroll
            for (int mt = 0; mt < 4; ++mt)
                #pragma unroll
                for (int nt = 0; nt < 4; ++nt)
                    acc[mt][nt] = __builtin_amdgcn_mfma_f32_16x16x32_f16(af[mt], bfr[nt], acc[mt][nt], 0, 0, 0);
        }
        __syncthreads();
    }
    #pragma unroll
    for (int nt = 0; nt < 4; ++nt) {
        int col = n0 + wc*64 + nt*16 + al;
        float bv = bias[col];
        #pragma unroll
        for (int mt = 0; mt < 4; ++mt)
            #pragma unroll
            for (int rg = 0; rg < 4; ++rg) {
                size_t row = (size_t)(m0 + wr*64 + mt*16 + g*4 + rg);
                outp[row * 512 + col] = acc[mt][nt][rg] + bv;
            }
    }
}

// ---------------- fused window attention (fp16, phase-grouped) ----------------
// grid (2048, 4). Window remap: XCD x only handles windows with (b&63)>>3 == x,
// so each XCD's cmb slice (8 wmods * 256KB = 2MB) stays L2-resident.
// Load order: Q,K first (QK-MFMA critical path), V after.
__global__ __launch_bounds__(256) void attn64(
    const u16* __restrict__ Q, const u16* __restrict__ Kb,
    const u16* __restrict__ Vth,
    const float* __restrict__ cmb,
    u16* __restrict__ Oout)
{
    __shared__ u16 Ph[4][64 * 72];
    const int bid = blockIdx.x;
    const int xcd = bid & 7, idx = bid >> 3;
    const int b = ((idx >> 3) << 6) | (xcd << 3) | (idx & 7);   // bijective
    const int tid = threadIdx.x;
    const int l = tid & 63, w = tid >> 6;
    const int al = l & 15, g = l >> 4;
    const size_t rbase = (size_t)b * 64;
    const int h = blockIdx.y * 4 + w;
    const int co = h * 32;

    f16x8 qf[4], kf[4];
    #pragma unroll
    for (int t = 0; t < 4; ++t) {
        qf[t] = *(const f16x8*)(Q  + (rbase + t*16 + al) * 512 + co + g*8);
        kf[t] = *(const f16x8*)(Kb + (rbase + t*16 + al) * 512 + co + g*8);
    }
    const u16* vth = Vth + ((size_t)b << 15) + (h << 11);
    f16x8 vhf[2][2];
    #pragma unroll
    for (int kt = 0; kt < 2; ++kt)
        #pragma unroll
        for (int dt = 0; dt < 2; ++dt) {
            int voff = ((dt*16 + al) << 6) + kt*32 + g*8;
            vhf[kt][dt] = *(const f16x8*)(vth + voff);
        }

    f32x4 s[4][4] = {};
    #pragma unroll
    for (int mt = 0; mt < 4; ++mt)
        #pragma unroll
        for (int nt = 0; nt < 4; ++nt)
            s[mt][nt] = __builtin_amdgcn_mfma_f32_16x16x32_f16(qf[mt], kf[nt], s[mt][nt], 0, 0, 0);

    const float* cp = cmb + ((((size_t)(b & 63)) * 16 + h) << 12);
    #pragma unroll
    for (int mt = 0; mt < 4; ++mt)
        #pragma unroll
        for (int nt = 0; nt < 4; ++nt) {
            f32x4 c4 = *(const f32x4*)(cp + ((nt*16 + al) << 6) + mt*16 + g*4);
            #pragma unroll
            for (int rg = 0; rg < 4; ++rg) s[mt][nt][rg] += c4[rg];
        }

    f32x4 sm[4];
    #pragma unroll
    for (int mt = 0; mt < 4; ++mt) {
        f32x4 m4 = s[mt][0];
        #pragma unroll
        for (int nt = 1; nt < 4; ++nt)
            #pragma unroll
            for (int c = 0; c < 4; ++c) m4[c] = fmaxf(m4[c], s[mt][nt][c]);
        #pragma unroll
        for (int d = 1; d < 16; d <<= 1)
            #pragma unroll
            for (int c = 0; c < 4; ++c) m4[c] = fmaxf(m4[c], shflx(m4[c], d));
        #pragma unroll
        for (int nt = 0; nt < 4; ++nt)
            #pragma unroll
            for (int rg = 0; rg < 4; ++rg)
                s[mt][nt][rg] = exp2f((s[mt][nt][rg] - m4[rg]) * LOG2E);
        f32x4 s4 = s[mt][0];
        #pragma unroll
        for (int nt = 1; nt < 4; ++nt) s4 += s[mt][nt];
        #pragma unroll
        for (int d = 1; d < 16; d <<= 1)
            #pragma unroll
            for (int c = 0; c < 4; ++c) s4[c] += shflx(s4[c], d);
        sm[mt] = s4;
    }

    #pragma unroll
    for (int mt = 0; mt < 4; ++mt)
        #pragma unroll
        for (int nt = 0; nt < 4; ++nt)
            #pragma unroll
            for (int rg = 0; rg < 4; ++rg) {
                int off = (mt*16 + g*4 + rg) * 72 + nt*16 + al;
                Ph[w][off] = f2h(s[mt][nt][rg]);
            }

    #pragma unroll
    for (int mt = 0; mt < 4; ++mt) {
        f16x8 pah[2];
        #pragma unroll
        for (int kt = 0; kt < 2; ++kt)
            pah[kt] = *(const f16x8*)&Ph[w][(mt*16 + al) * 72 + kt*32 + g*8];
        f32x4 o[2] = {};
        #pragma unroll
        for (int dt = 0; dt < 2; ++dt)
            #pragma unroll
            for (int kt = 0; kt < 2; ++kt)
                o[dt] = __builtin_amdgcn_mfma_f32_16x16x32_f16(pah[kt], vhf[kt][dt], o[dt], 0, 0, 0);
        #pragma unroll
        for (int dt = 0; dt < 2; ++dt)
            #pragma unroll
            for (int rg = 0; rg < 4; ++rg) {
                float inv = __builtin_amdgcn_rcpf(sm[mt][rg]);
                float v = o[dt][rg] * inv;
                size_t off = (rbase + mt*16 + g*4 + rg) * 512 + co + dt*16 + al;
                Oout[off] = f2h(v);
            }
    }
}

// ---------------- launch ----------------
extern "C" void kernel_launch(void* const* d_in, const int* in_sizes, int n_in,
                              void* d_out, int out_size, void* d_ws, size_t ws_size,
                              hipStream_t stream)
{
    const float* x      = (const float*)d_in[0];
    const float* y      = (const float*)d_in[1];
    const float* mask   = (const float*)d_in[2];
    const float* W_q    = (const float*)d_in[3];
    const float* b_q    = (const float*)d_in[4];
    const float* W_kv   = (const float*)d_in[5];
    const float* b_kv   = (const float*)d_in[6];
    const float* W_proj = (const float*)d_in[7];
    const float* b_proj = (const float*)d_in[8];
    const float* table  = (const float*)d_in[9];

    char* ws = (char*)d_ws;
    const size_t SEG = (size_t)MROWS * 512 * sizeof(u16);   // 128 MB
    u16* Qs     = (u16*)(ws);              // aliased by O after attention
    u16* Ks     = (u16*)(ws + SEG);
    u16* Vth    = (u16*)(ws + 2 * SEG);    // V^T [win][h][d][k], fp16
    u16* wqT    = (u16*)(ws + 3 * SEG);
    u16* wkvKT  = wqT    + 512 * 512;
    u16* wkvVT  = wkvKT  + 512 * 512;
    u16* wprT   = wkvVT  + 512 * 512;
    float* cmb  = (float*)(wprT + 512 * 512);   // 64*16*4096*4B = 16 MB

    wt_all<<<dim3(1024, 4), 256, 0, stream>>>(W_q, W_kv, W_proj, wqT, wkvKT, wkvVT, wprT);
    cmb_pre<<<dim3(64, 16), 256, 0, stream>>>(table, mask, cmb);

    gemm_qk<<<4096, 256, 0, stream>>>(x, wqT, b_q, Qs, QSCALE);
    gemm_qk<<<4096, 256, 0, stream>>>(y, wkvKT, b_kv, Ks, 1.0f);
    gemm_v<<<4096, 256, 0, stream>>>(y, wkvVT, b_kv + 512, Vth);
    attn64<<<dim3(2048, 4), 256, 0, stream>>>(Qs, Ks, Vth, cmb, Qs);
    gemm_proj<<<4096, 256, 0, stream>>>(Qs, wprT, b_proj, (float*)d_out);
}

// Round 17
// 727.252 us; speedup vs baseline: 1.0777x; 1.0777x over previous
//
#include <hip/hip_runtime.h>
#include <stdint.h>

#define MROWS 131072                     // 2048 windows * 64 tokens
#define LOG2E 1.44269504088896340736f
#define QSCALE 0.17677669529663688110f   // 32^-0.5

typedef _Float16 f16x8 __attribute__((ext_vector_type(8)));
typedef float f32x4 __attribute__((ext_vector_type(4)));
typedef unsigned short u16;
typedef u16 u16x4 __attribute__((ext_vector_type(4)));
typedef u16 u16x8 __attribute__((ext_vector_type(8)));

#define GLD16(gp, lp) __builtin_amdgcn_global_load_lds( \
    (const __attribute__((address_space(1))) void*)(gp), \
    (__attribute__((address_space(3))) void*)(lp), 16, 0, 0)

static __device__ __forceinline__ u16 f2h(float f) {
    _Float16 h = (_Float16)f;             // RNE
    return __builtin_bit_cast(unsigned short, h);
}
static __device__ __forceinline__ float shflx(float v, int m) {
    return __shfl_xor(v, m, 64);
}
// bijective XCD swizzles (grid % 8 == 0)
static __device__ __forceinline__ int swz4096(int bid) {
    return (bid & 7) * 512 + (bid >> 3);
}
static __device__ __forceinline__ int swz8192(int bid) {
    return (bid & 7) * 1024 + (bid >> 3);
}

// ---------------- setup kernels ----------------
// weight transposes: wqT[512x512], wkvT[1024x512] (K cols then V cols), wprT[512x512]
__global__ void wt_all(const float* __restrict__ Wq, const float* __restrict__ Wkv,
                       const float* __restrict__ Wp,
                       u16* __restrict__ wqT, u16* __restrict__ wkvT,
                       u16* __restrict__ wprT) {
    int idx = blockIdx.x * 256 + threadIdx.x;
    int n = idx >> 9, k = idx & 511;
    switch (blockIdx.y) {
        case 0: wqT[idx] = f2h(Wq[(size_t)k * 512 + n]); break;
        case 1: wkvT[idx] = f2h(Wkv[(size_t)k * 1024 + n]); break;
        case 2: wkvT[262144 + idx] = f2h(Wkv[(size_t)k * 1024 + 512 + n]); break;
        default: wprT[idx] = f2h(Wp[(size_t)k * 512 + n]); break;
    }
}
// combined (rel-pos bias + shift mask), stored TRANSPOSED: cmb[wmod][h][j][i]
__global__ void cmb_pre(const float* __restrict__ table, const float* __restrict__ mask,
                        float* __restrict__ cmb) {
    int wmod = blockIdx.x, h = blockIdx.y;
    float* outp = cmb + (((size_t)wmod * 16 + h) << 12);
    const float* mp = mask + ((size_t)wmod << 12);
    for (int e = threadIdx.x; e < 4096; e += 256) {
        int j = e >> 6, i = e & 63;
        int idx = ((i >> 3) - (j >> 3) + 7) * 15 + ((i & 7) - (j & 7) + 7);
        outp[e] = table[idx * 16 + h] + mp[i * 64 + j];
    }
}

// ---------------- Q GEMM: BK=32, A fp32 reg-staged -> fp16 LDS, B via gld_lds
__global__ __launch_bounds__(256, 4) void gemm_qk(
    const float* __restrict__ A, const u16* __restrict__ BT,
    const float* __restrict__ bias, u16* __restrict__ outp, float scale)
{
    __shared__ u16 As[128 * 32];
    __shared__ u16 Bs[128 * 32];
    const int tid = threadIdx.x;
    const int l = tid & 63, w = tid >> 6;
    const int al = l & 15, g = l >> 4;
    const int wr = w >> 1, wc = w & 1;
    const int wg = swz4096(blockIdx.x);
    const int n0 = (wg & 3) * 128, m0 = (wg >> 2) * 128;
    const int srow = tid >> 2, sc8 = (tid & 3) * 8;
    f32x4 acc[4][4] = {};

    for (int kk = 0; kk < 512; kk += 32) {
        #pragma unroll
        for (int r = 0; r < 2; ++r) {
            int row = r * 64 + srow;
            GLD16(BT + (size_t)(n0 + row) * 512 + kk + sc8, &Bs[row * 32 + sc8]);
            const float* ap = A + (size_t)(m0 + row) * 512 + kk + sc8;
            f32x4 v0 = *(const f32x4*)(ap);
            f32x4 v1 = *(const f32x4*)(ap + 4);
            u16x8 hv;
            hv[0]=f2h(v0[0]); hv[1]=f2h(v0[1]); hv[2]=f2h(v0[2]); hv[3]=f2h(v0[3]);
            hv[4]=f2h(v1[0]); hv[5]=f2h(v1[1]); hv[6]=f2h(v1[2]); hv[7]=f2h(v1[3]);
            *(u16x8*)&As[row * 32 + sc8] = hv;
        }
        __syncthreads();
        {
            f16x8 af[4], bfr[4];
            #pragma unroll
            for (int mt = 0; mt < 4; ++mt)
                af[mt] = *(const f16x8*)&As[(wr*64 + mt*16 + al) * 32 + g*8];
            #pragma unroll
            for (int nt = 0; nt < 4; ++nt)
                bfr[nt] = *(const f16x8*)&Bs[(wc*64 + nt*16 + al) * 32 + g*8];
            #pragma unroll
            for (int mt = 0; mt < 4; ++mt)
                #pragma unroll
                for (int nt = 0; nt < 4; ++nt)
                    acc[mt][nt] = __builtin_amdgcn_mfma_f32_16x16x32_f16(af[mt], bfr[nt], acc[mt][nt], 0, 0, 0);
        }
        __syncthreads();
    }
    #pragma unroll
    for (int nt = 0; nt < 4; ++nt) {
        int col = n0 + wc*64 + nt*16 + al;
        float bv = bias[col];
        #pragma unroll
        for (int mt = 0; mt < 4; ++mt)
            #pragma unroll
            for (int rg = 0; rg < 4; ++rg) {
                size_t row = (size_t)(m0 + wr*64 + mt*16 + g*4 + rg);
                outp[row * 512 + col] = f2h((acc[mt][nt][rg] + bv) * scale);
            }
    }
}

// ---------------- y GEMM (K+V in one grid): N=1024, 8192 blocks of the proven
// 128x128 shape; per-block epilogue switch (K row-major / V^T scatter).
__global__ __launch_bounds__(256, 4) void gemm_y(
    const float* __restrict__ A, const u16* __restrict__ BT,
    const float* __restrict__ bias,      // b_kv, 1024
    u16* __restrict__ Kout, u16* __restrict__ Vout)
{
    __shared__ u16 As[128 * 32];
    __shared__ u16 Bs[128 * 32];
    const int tid = threadIdx.x;
    const int l = tid & 63, w = tid >> 6;
    const int al = l & 15, g = l >> 4;
    const int wr = w >> 1, wc = w & 1;
    const int wg = swz8192(blockIdx.x);
    const int n0 = (wg & 7) * 128, m0 = (wg >> 3) * 128;
    const int srow = tid >> 2, sc8 = (tid & 3) * 8;
    f32x4 acc[4][4] = {};

    for (int kk = 0; kk < 512; kk += 32) {
        #pragma unroll
        for (int r = 0; r < 2; ++r) {
            int row = r * 64 + srow;
            GLD16(BT + (size_t)(n0 + row) * 512 + kk + sc8, &Bs[row * 32 + sc8]);
            const float* ap = A + (size_t)(m0 + row) * 512 + kk + sc8;
            f32x4 v0 = *(const f32x4*)(ap);
            f32x4 v1 = *(const f32x4*)(ap + 4);
            u16x8 hv;
            hv[0]=f2h(v0[0]); hv[1]=f2h(v0[1]); hv[2]=f2h(v0[2]); hv[3]=f2h(v0[3]);
            hv[4]=f2h(v1[0]); hv[5]=f2h(v1[1]); hv[6]=f2h(v1[2]); hv[7]=f2h(v1[3]);
            *(u16x8*)&As[row * 32 + sc8] = hv;
        }
        __syncthreads();
        {
            f16x8 af[4], bfr[4];
            #pragma unroll
            for (int mt = 0; mt < 4; ++mt)
                af[mt] = *(const f16x8*)&As[(wr*64 + mt*16 + al) * 32 + g*8];
            #pragma unroll
            for (int nt = 0; nt < 4; ++nt)
                bfr[nt] = *(const f16x8*)&Bs[(wc*64 + nt*16 + al) * 32 + g*8];
            #pragma unroll
            for (int mt = 0; mt < 4; ++mt)
                #pragma unroll
                for (int nt = 0; nt < 4; ++nt)
                    acc[mt][nt] = __builtin_amdgcn_mfma_f32_16x16x32_f16(af[mt], bfr[nt], acc[mt][nt], 0, 0, 0);
        }
        __syncthreads();
    }
    if (n0 < 512) {
        // K epilogue: row-major fp16, ld 512
        #pragma unroll
        for (int nt = 0; nt < 4; ++nt) {
            int col = n0 + wc*64 + nt*16 + al;
            float bv = bias[col];
            #pragma unroll
            for (int mt = 0; mt < 4; ++mt)
                #pragma unroll
                for (int rg = 0; rg < 4; ++rg) {
                    size_t row = (size_t)(m0 + wr*64 + mt*16 + g*4 + rg);
                    Kout[row * 512 + col] = f2h(acc[mt][nt][rg] + bv);
                }
        }
    } else {
        // V epilogue: V^T per head [window][h][d(32)][k(64)]
        #pragma unroll
        for (int nt = 0; nt < 4; ++nt) {
            int col = n0 + wc*64 + nt*16 + al;       // 512..1023
            int c2 = col - 512;
            int hh_ = c2 >> 5, d = c2 & 31;
            float bv = bias[col];
            #pragma unroll
            for (int mt = 0; mt < 4; ++mt) {
                int row0 = m0 + wr*64 + mt*16 + g*4;
                int window = row0 >> 6, k0 = row0 & 63;
                size_t off = ((size_t)window << 15) + (hh_ << 11) + (d << 6) + k0;
                u16x4 hv;
                #pragma unroll
                for (int rg = 0; rg < 4; ++rg)
                    hv[rg] = f2h(acc[mt][nt][rg] + bv);
                *(u16x4*)(Vout + off) = hv;
            }
        }
    }
}

// ---------------- proj GEMM: BK=32, A (fp16 O) + B via global_load_lds, fp32 out
__global__ __launch_bounds__(256, 4) void gemm_proj(
    const u16* __restrict__ A1, const u16* __restrict__ BT,
    const float* __restrict__ bias, float* __restrict__ outp)
{
    __shared__ u16 As[128*32], Bs[128*32];
    const int tid = threadIdx.x;
    const int l = tid & 63, w = tid >> 6;
    const int al = l & 15, g = l >> 4;
    const int wr = w >> 1, wc = w & 1;
    const int wg = swz4096(blockIdx.x);
    const int n0 = (wg & 3) * 128, m0 = (wg >> 2) * 128;
    const int srow = tid >> 2, sc8 = (tid & 3) * 8;
    f32x4 acc[4][4] = {};

    for (int kk = 0; kk < 512; kk += 32) {
        #pragma unroll
        for (int r = 0; r < 2; ++r) {
            int row = r * 64 + srow;
            size_t aoff = (size_t)(m0 + row) * 512 + kk + sc8;
            size_t boff = (size_t)(n0 + row) * 512 + kk + sc8;
            int loff = row * 32 + sc8;
            GLD16(A1 + aoff, &As[loff]);
            GLD16(BT + boff, &Bs[loff]);
        }
        __syncthreads();
        {
            f16x8 af[4], bfr[4];
            #pragma unroll
            for (int mt = 0; mt < 4; ++mt)
                af[mt] = *(const f16x8*)&As[(wr*64 + mt*16 + al) * 32 + g*8];
            #pragma unroll
            for (int nt = 0; nt < 4; ++nt)
                bfr[nt] = *(const f16x8*)&Bs[(wc*64 + nt*16 + al) * 32 + g*8];
            #pragma unroll
            for (int mt = 0; mt < 4; ++mt)
                #pragma unroll
                for (int nt = 0; nt < 4; ++nt)
                    acc[mt][nt] = __builtin_amdgcn_mfma_f32_16x16x32_f16(af[mt], bfr[nt], acc[mt][nt], 0, 0, 0);
        }
        __syncthreads();
    }
    #pragma unroll
    for (int nt = 0; nt < 4; ++nt) {
        int col = n0 + wc*64 + nt*16 + al;
        float bv = bias[col];
        #pragma unroll
        for (int mt = 0; mt < 4; ++mt)
            #pragma unroll
            for (int rg = 0; rg < 4; ++rg) {
                size_t row = (size_t)(m0 + wr*64 + mt*16 + g*4 + rg);
                outp[row * 512 + col] = acc[mt][nt][rg] + bv;
            }
    }
}

// ---------------- fused window attention (fp16, phase-grouped) ----------------
// grid (2048, 4). Window remap: XCD x only handles windows with (b&63)>>3 == x,
// so each XCD's cmb slice (8 wmods * 256KB = 2MB) stays L2-resident.
// Load order: Q,K first (QK-MFMA critical path), V after.
__global__ __launch_bounds__(256) void attn64(
    const u16* __restrict__ Q, const u16* __restrict__ Kb,
    const u16* __restrict__ Vth,
    const float* __restrict__ cmb,
    u16* __restrict__ Oout)
{
    __shared__ u16 Ph[4][64 * 72];
    const int bid = blockIdx.x;
    const int xcd = bid & 7, idx = bid >> 3;
    const int b = ((idx >> 3) << 6) | (xcd << 3) | (idx & 7);   // bijective
    const int tid = threadIdx.x;
    const int l = tid & 63, w = tid >> 6;
    const int al = l & 15, g = l >> 4;
    const size_t rbase = (size_t)b * 64;
    const int h = blockIdx.y * 4 + w;
    const int co = h * 32;

    f16x8 qf[4], kf[4];
    #pragma unroll
    for (int t = 0; t < 4; ++t) {
        qf[t] = *(const f16x8*)(Q  + (rbase + t*16 + al) * 512 + co + g*8);
        kf[t] = *(const f16x8*)(Kb + (rbase + t*16 + al) * 512 + co + g*8);
    }
    const u16* vth = Vth + ((size_t)b << 15) + (h << 11);
    f16x8 vhf[2][2];
    #pragma unroll
    for (int kt = 0; kt < 2; ++kt)
        #pragma unroll
        for (int dt = 0; dt < 2; ++dt) {
            int voff = ((dt*16 + al) << 6) + kt*32 + g*8;
            vhf[kt][dt] = *(const f16x8*)(vth + voff);
        }

    f32x4 s[4][4] = {};
    #pragma unroll
    for (int mt = 0; mt < 4; ++mt)
        #pragma unroll
        for (int nt = 0; nt < 4; ++nt)
            s[mt][nt] = __builtin_amdgcn_mfma_f32_16x16x32_f16(qf[mt], kf[nt], s[mt][nt], 0, 0, 0);

    const float* cp = cmb + ((((size_t)(b & 63)) * 16 + h) << 12);
    #pragma unroll
    for (int mt = 0; mt < 4; ++mt)
        #pragma unroll
        for (int nt = 0; nt < 4; ++nt) {
            f32x4 c4 = *(const f32x4*)(cp + ((nt*16 + al) << 6) + mt*16 + g*4);
            #pragma unroll
            for (int rg = 0; rg < 4; ++rg) s[mt][nt][rg] += c4[rg];
        }

    f32x4 sm[4];
    #pragma unroll
    for (int mt = 0; mt < 4; ++mt) {
        f32x4 m4 = s[mt][0];
        #pragma unroll
        for (int nt = 1; nt < 4; ++nt)
            #pragma unroll
            for (int c = 0; c < 4; ++c) m4[c] = fmaxf(m4[c], s[mt][nt][c]);
        #pragma unroll
        for (int d = 1; d < 16; d <<= 1)
            #pragma unroll
            for (int c = 0; c < 4; ++c) m4[c] = fmaxf(m4[c], shflx(m4[c], d));
        #pragma unroll
        for (int nt = 0; nt < 4; ++nt)
            #pragma unroll
            for (int rg = 0; rg < 4; ++rg)
                s[mt][nt][rg] = exp2f((s[mt][nt][rg] - m4[rg]) * LOG2E);
        f32x4 s4 = s[mt][0];
        #pragma unroll
        for (int nt = 1; nt < 4; ++nt) s4 += s[mt][nt];
        #pragma unroll
        for (int d = 1; d < 16; d <<= 1)
            #pragma unroll
            for (int c = 0; c < 4; ++c) s4[c] += shflx(s4[c], d);
        sm[mt] = s4;
    }

    #pragma unroll
    for (int mt = 0; mt < 4; ++mt)
        #pragma unroll
        for (int nt = 0; nt < 4; ++nt)
            #pragma unroll
            for (int rg = 0; rg < 4; ++rg) {
                int off = (mt*16 + g*4 + rg) * 72 + nt*16 + al;
                Ph[w][off] = f2h(s[mt][nt][rg]);
            }

    #pragma unroll
    for (int mt = 0; mt < 4; ++mt) {
        f16x8 pah[2];
        #pragma unroll
        for (int kt = 0; kt < 2; ++kt)
            pah[kt] = *(const f16x8*)&Ph[w][(mt*16 + al) * 72 + kt*32 + g*8];
        f32x4 o[2] = {};
        #pragma unroll
        for (int dt = 0; dt < 2; ++dt)
            #pragma unroll
            for (int kt = 0; kt < 2; ++kt)
                o[dt] = __builtin_amdgcn_mfma_f32_16x16x32_f16(pah[kt], vhf[kt][dt], o[dt], 0, 0, 0);
        #pragma unroll
        for (int dt = 0; dt < 2; ++dt)
            #pragma unroll
            for (int rg = 0; rg < 4; ++rg) {
                float inv = __builtin_amdgcn_rcpf(sm[mt][rg]);
                float v = o[dt][rg] * inv;
                size_t off = (rbase + mt*16 + g*4 + rg) * 512 + co + dt*16 + al;
                Oout[off] = f2h(v);
            }
    }
}

// ---------------- launch ----------------
extern "C" void kernel_launch(void* const* d_in, const int* in_sizes, int n_in,
                              void* d_out, int out_size, void* d_ws, size_t ws_size,
                              hipStream_t stream)
{
    const float* x      = (const float*)d_in[0];
    const float* y      = (const float*)d_in[1];
    const float* mask   = (const float*)d_in[2];
    const float* W_q    = (const float*)d_in[3];
    const float* b_q    = (const float*)d_in[4];
    const float* W_kv   = (const float*)d_in[5];
    const float* b_kv   = (const float*)d_in[6];
    const float* W_proj = (const float*)d_in[7];
    const float* b_proj = (const float*)d_in[8];
    const float* table  = (const float*)d_in[9];

    char* ws = (char*)d_ws;
    const size_t SEG = (size_t)MROWS * 512 * sizeof(u16);   // 128 MB
    u16* Qs     = (u16*)(ws);              // aliased by O after attention
    u16* Ks     = (u16*)(ws + SEG);
    u16* Vth    = (u16*)(ws + 2 * SEG);    // V^T [win][h][d][k], fp16
    u16* wqT    = (u16*)(ws + 3 * SEG);
    u16* wkvT   = wqT  + 512 * 512;        // [1024][512] (K cols, then V cols)
    u16* wprT   = wkvT + 1024 * 512;
    float* cmb  = (float*)(wprT + 512 * 512);   // 64*16*4096*4B = 16 MB

    wt_all<<<dim3(1024, 4), 256, 0, stream>>>(W_q, W_kv, W_proj, wqT, wkvT, wprT);
    cmb_pre<<<dim3(64, 16), 256, 0, stream>>>(table, mask, cmb);

    gemm_qk<<<4096, 256, 0, stream>>>(x, wqT, b_q, Qs, QSCALE);
    gemm_y<<<8192, 256, 0, stream>>>(y, wkvT, b_kv, Ks, Vth);
    attn64<<<dim3(2048, 4), 256, 0, stream>>>(Qs, Ks, Vth, cmb, Qs);
    gemm_proj<<<4096, 256, 0, stream>>>(Qs, wprT, b_proj, (float*)d_out);
}

// Round 18
// 709.500 us; speedup vs baseline: 1.1046x; 1.0250x over previous
//
#include <hip/hip_runtime.h>
#include <stdint.h>

#define MROWS 131072                     // 2048 windows * 64 tokens
#define LOG2E 1.44269504088896340736f
#define QSCALE 0.17677669529663688110f   // 32^-0.5

typedef _Float16 f16x8 __attribute__((ext_vector_type(8)));
typedef float f32x4 __attribute__((ext_vector_type(4)));
typedef unsigned short u16;
typedef u16 u16x4 __attribute__((ext_vector_type(4)));
typedef u16 u16x8 __attribute__((ext_vector_type(8)));

#define GLD16(gp, lp) __builtin_amdgcn_global_load_lds( \
    (const __attribute__((address_space(1))) void*)(gp), \
    (__attribute__((address_space(3))) void*)(lp), 16, 0, 0)

static __device__ __forceinline__ u16 f2h(float f) {
    _Float16 h = (_Float16)f;             // RNE
    return __builtin_bit_cast(unsigned short, h);
}
static __device__ __forceinline__ float shflx(float v, int m) {
    return __shfl_xor(v, m, 64);
}
// bijective XCD swizzles (grid % 8 == 0)
static __device__ __forceinline__ int swz4096(int bid) {
    return (bid & 7) * 512 + (bid >> 3);
}
static __device__ __forceinline__ int swz12288(int bid) {
    return (bid & 7) * 1536 + (bid >> 3);
}

// ---------------- setup kernels ----------------
// weight transposes: wqT[512x512], wkvT[1024x512] (K cols then V cols), wprT[512x512]
__global__ void wt_all(const float* __restrict__ Wq, const float* __restrict__ Wkv,
                       const float* __restrict__ Wp,
                       u16* __restrict__ wqT, u16* __restrict__ wkvT,
                       u16* __restrict__ wprT) {
    int idx = blockIdx.x * 256 + threadIdx.x;
    int n = idx >> 9, k = idx & 511;
    switch (blockIdx.y) {
        case 0: wqT[idx] = f2h(Wq[(size_t)k * 512 + n]); break;
        case 1: wkvT[idx] = f2h(Wkv[(size_t)k * 1024 + n]); break;
        case 2: wkvT[262144 + idx] = f2h(Wkv[(size_t)k * 1024 + 512 + n]); break;
        default: wprT[idx] = f2h(Wp[(size_t)k * 512 + n]); break;
    }
}
// combined (rel-pos bias + shift mask), stored TRANSPOSED: cmb[wmod][h][j][i]
__global__ void cmb_pre(const float* __restrict__ table, const float* __restrict__ mask,
                        float* __restrict__ cmb) {
    int wmod = blockIdx.x, h = blockIdx.y;
    float* outp = cmb + (((size_t)wmod * 16 + h) << 12);
    const float* mp = mask + ((size_t)wmod << 12);
    for (int e = threadIdx.x; e < 4096; e += 256) {
        int j = e >> 6, i = e & 63;
        int idx = ((i >> 3) - (j >> 3) + 7) * 15 + ((i & 7) - (j & 7) + 7);
        outp[e] = table[idx * 16 + h] + mp[i * 64 + j];
    }
}

// ---------------- unified projection GEMM (Q from x; K,V from y), 12288 blocks
// wg = m*12 + n;  n 0-3: Q (out Qs, *QSCALE) | 4-7: K row-major | 8-11: V^T.
__global__ __launch_bounds__(256, 4) void gemm_xy(
    const float* __restrict__ x, const float* __restrict__ y,
    const u16* __restrict__ wqT, const u16* __restrict__ wkvT,
    const float* __restrict__ b_q, const float* __restrict__ b_kv,
    u16* __restrict__ Qs, u16* __restrict__ Kout, u16* __restrict__ Vout)
{
    __shared__ u16 As[128 * 32];
    __shared__ u16 Bs[128 * 32];
    const int tid = threadIdx.x;
    const int l = tid & 63, w = tid >> 6;
    const int al = l & 15, g = l >> 4;
    const int wr = w >> 1, wc = w & 1;
    const int wg = swz12288(blockIdx.x);
    const int nidx = wg % 12;
    const int m0 = (wg / 12) * 128;
    const bool isQ = (nidx < 4);
    const float* A = isQ ? x : y;
    const u16* BT = isQ ? wqT : wkvT;
    const int n0 = (isQ ? nidx : nidx - 4) * 128;
    const int srow = tid >> 2, sc8 = (tid & 3) * 8;
    f32x4 acc[4][4] = {};

    for (int kk = 0; kk < 512; kk += 32) {
        #pragma unroll
        for (int r = 0; r < 2; ++r) {
            int row = r * 64 + srow;
            GLD16(BT + (size_t)(n0 + row) * 512 + kk + sc8, &Bs[row * 32 + sc8]);
            const float* ap = A + (size_t)(m0 + row) * 512 + kk + sc8;
            f32x4 v0 = *(const f32x4*)(ap);
            f32x4 v1 = *(const f32x4*)(ap + 4);
            u16x8 hv;
            hv[0]=f2h(v0[0]); hv[1]=f2h(v0[1]); hv[2]=f2h(v0[2]); hv[3]=f2h(v0[3]);
            hv[4]=f2h(v1[0]); hv[5]=f2h(v1[1]); hv[6]=f2h(v1[2]); hv[7]=f2h(v1[3]);
            *(u16x8*)&As[row * 32 + sc8] = hv;
        }
        __syncthreads();
        {
            f16x8 af[4], bfr[4];
            #pragma unroll
            for (int mt = 0; mt < 4; ++mt)
                af[mt] = *(const f16x8*)&As[(wr*64 + mt*16 + al) * 32 + g*8];
            #pragma unroll
            for (int nt = 0; nt < 4; ++nt)
                bfr[nt] = *(const f16x8*)&Bs[(wc*64 + nt*16 + al) * 32 + g*8];
            #pragma unroll
            for (int mt = 0; mt < 4; ++mt)
                #pragma unroll
                for (int nt = 0; nt < 4; ++nt)
                    acc[mt][nt] = __builtin_amdgcn_mfma_f32_16x16x32_f16(af[mt], bfr[nt], acc[mt][nt], 0, 0, 0);
        }
        __syncthreads();
    }
    if (isQ) {
        #pragma unroll
        for (int nt = 0; nt < 4; ++nt) {
            int col = n0 + wc*64 + nt*16 + al;
            float bv = b_q[col];
            #pragma unroll
            for (int mt = 0; mt < 4; ++mt)
                #pragma unroll
                for (int rg = 0; rg < 4; ++rg) {
                    size_t row = (size_t)(m0 + wr*64 + mt*16 + g*4 + rg);
                    Qs[row * 512 + col] = f2h((acc[mt][nt][rg] + bv) * QSCALE);
                }
        }
    } else if (nidx < 8) {
        // K epilogue: row-major fp16, ld 512
        #pragma unroll
        for (int nt = 0; nt < 4; ++nt) {
            int col = n0 + wc*64 + nt*16 + al;
            float bv = b_kv[col];
            #pragma unroll
            for (int mt = 0; mt < 4; ++mt)
                #pragma unroll
                for (int rg = 0; rg < 4; ++rg) {
                    size_t row = (size_t)(m0 + wr*64 + mt*16 + g*4 + rg);
                    Kout[row * 512 + col] = f2h(acc[mt][nt][rg] + bv);
                }
        }
    } else {
        // V epilogue: V^T per head [window][h][d(32)][k(64)]
        #pragma unroll
        for (int nt = 0; nt < 4; ++nt) {
            int col = n0 + wc*64 + nt*16 + al;       // 512..1023
            int c2 = col - 512;
            int hh_ = c2 >> 5, d = c2 & 31;
            float bv = b_kv[col];
            #pragma unroll
            for (int mt = 0; mt < 4; ++mt) {
                int row0 = m0 + wr*64 + mt*16 + g*4;
                int window = row0 >> 6, k0 = row0 & 63;
                size_t off = ((size_t)window << 15) + (hh_ << 11) + (d << 6) + k0;
                u16x4 hv;
                #pragma unroll
                for (int rg = 0; rg < 4; ++rg)
                    hv[rg] = f2h(acc[mt][nt][rg] + bv);
                *(u16x4*)(Vout + off) = hv;
            }
        }
    }
}

// ---------------- proj GEMM: BK=32, A (fp16 O) + B via global_load_lds, fp32 out
__global__ __launch_bounds__(256, 4) void gemm_proj(
    const u16* __restrict__ A1, const u16* __restrict__ BT,
    const float* __restrict__ bias, float* __restrict__ outp)
{
    __shared__ u16 As[128*32], Bs[128*32];
    const int tid = threadIdx.x;
    const int l = tid & 63, w = tid >> 6;
    const int al = l & 15, g = l >> 4;
    const int wr = w >> 1, wc = w & 1;
    const int wg = swz4096(blockIdx.x);
    const int n0 = (wg & 3) * 128, m0 = (wg >> 2) * 128;
    const int srow = tid >> 2, sc8 = (tid & 3) * 8;
    f32x4 acc[4][4] = {};

    for (int kk = 0; kk < 512; kk += 32) {
        #pragma unroll
        for (int r = 0; r < 2; ++r) {
            int row = r * 64 + srow;
            size_t aoff = (size_t)(m0 + row) * 512 + kk + sc8;
            size_t boff = (size_t)(n0 + row) * 512 + kk + sc8;
            int loff = row * 32 + sc8;
            GLD16(A1 + aoff, &As[loff]);
            GLD16(BT + boff, &Bs[loff]);
        }
        __syncthreads();
        {
            f16x8 af[4], bfr[4];
            #pragma unroll
            for (int mt = 0; mt < 4; ++mt)
                af[mt] = *(const f16x8*)&As[(wr*64 + mt*16 + al) * 32 + g*8];
            #pragma unroll
            for (int nt = 0; nt < 4; ++nt)
                bfr[nt] = *(const f16x8*)&Bs[(wc*64 + nt*16 + al) * 32 + g*8];
            #pragma unroll
            for (int mt = 0; mt < 4; ++mt)
                #pragma unroll
                for (int nt = 0; nt < 4; ++nt)
                    acc[mt][nt] = __builtin_amdgcn_mfma_f32_16x16x32_f16(af[mt], bfr[nt], acc[mt][nt], 0, 0, 0);
        }
        __syncthreads();
    }
    #pragma unroll
    for (int nt = 0; nt < 4; ++nt) {
        int col = n0 + wc*64 + nt*16 + al;
        float bv = bias[col];
        #pragma unroll
        for (int mt = 0; mt < 4; ++mt)
            #pragma unroll
            for (int rg = 0; rg < 4; ++rg) {
                size_t row = (size_t)(m0 + wr*64 + mt*16 + g*4 + rg);
                outp[row * 512 + col] = acc[mt][nt][rg] + bv;
            }
    }
}

// ---------------- fused window attention (fp16, phase-grouped) ----------------
// grid (2048, 4). Window remap: XCD x only handles windows with (b&63)>>3 == x,
// so each XCD's cmb slice (8 wmods * 256KB = 2MB) stays L2-resident.
// Load order: Q,K first (QK-MFMA critical path), V after.
__global__ __launch_bounds__(256) void attn64(
    const u16* __restrict__ Q, const u16* __restrict__ Kb,
    const u16* __restrict__ Vth,
    const float* __restrict__ cmb,
    u16* __restrict__ Oout)
{
    __shared__ u16 Ph[4][64 * 72];
    const int bid = blockIdx.x;
    const int xcd = bid & 7, idx = bid >> 3;
    const int b = ((idx >> 3) << 6) | (xcd << 3) | (idx & 7);   // bijective
    const int tid = threadIdx.x;
    const int l = tid & 63, w = tid >> 6;
    const int al = l & 15, g = l >> 4;
    const size_t rbase = (size_t)b * 64;
    const int h = blockIdx.y * 4 + w;
    const int co = h * 32;

    f16x8 qf[4], kf[4];
    #pragma unroll
    for (int t = 0; t < 4; ++t) {
        qf[t] = *(const f16x8*)(Q  + (rbase + t*16 + al) * 512 + co + g*8);
        kf[t] = *(const f16x8*)(Kb + (rbase + t*16 + al) * 512 + co + g*8);
    }
    const u16* vth = Vth + ((size_t)b << 15) + (h << 11);
    f16x8 vhf[2][2];
    #pragma unroll
    for (int kt = 0; kt < 2; ++kt)
        #pragma unroll
        for (int dt = 0; dt < 2; ++dt) {
            int voff = ((dt*16 + al) << 6) + kt*32 + g*8;
            vhf[kt][dt] = *(const f16x8*)(vth + voff);
        }

    f32x4 s[4][4] = {};
    #pragma unroll
    for (int mt = 0; mt < 4; ++mt)
        #pragma unroll
        for (int nt = 0; nt < 4; ++nt)
            s[mt][nt] = __builtin_amdgcn_mfma_f32_16x16x32_f16(qf[mt], kf[nt], s[mt][nt], 0, 0, 0);

    const float* cp = cmb + ((((size_t)(b & 63)) * 16 + h) << 12);
    #pragma unroll
    for (int mt = 0; mt < 4; ++mt)
        #pragma unroll
        for (int nt = 0; nt < 4; ++nt) {
            f32x4 c4 = *(const f32x4*)(cp + ((nt*16 + al) << 6) + mt*16 + g*4);
            #pragma unroll
            for (int rg = 0; rg < 4; ++rg) s[mt][nt][rg] += c4[rg];
        }

    f32x4 sm[4];
    #pragma unroll
    for (int mt = 0; mt < 4; ++mt) {
        f32x4 m4 = s[mt][0];
        #pragma unroll
        for (int nt = 1; nt < 4; ++nt)
            #pragma unroll
            for (int c = 0; c < 4; ++c) m4[c] = fmaxf(m4[c], s[mt][nt][c]);
        #pragma unroll
        for (int d = 1; d < 16; d <<= 1)
            #pragma unroll
            for (int c = 0; c < 4; ++c) m4[c] = fmaxf(m4[c], shflx(m4[c], d));
        #pragma unroll
        for (int nt = 0; nt < 4; ++nt)
            #pragma unroll
            for (int rg = 0; rg < 4; ++rg)
                s[mt][nt][rg] = exp2f((s[mt][nt][rg] - m4[rg]) * LOG2E);
        f32x4 s4 = s[mt][0];
        #pragma unroll
        for (int nt = 1; nt < 4; ++nt) s4 += s[mt][nt];
        #pragma unroll
        for (int d = 1; d < 16; d <<= 1)
            #pragma unroll
            for (int c = 0; c < 4; ++c) s4[c] += shflx(s4[c], d);
        sm[mt] = s4;
    }

    #pragma unroll
    for (int mt = 0; mt < 4; ++mt)
        #pragma unroll
        for (int nt = 0; nt < 4; ++nt)
            #pragma unroll
            for (int rg = 0; rg < 4; ++rg) {
                int off = (mt*16 + g*4 + rg) * 72 + nt*16 + al;
                Ph[w][off] = f2h(s[mt][nt][rg]);
            }

    #pragma unroll
    for (int mt = 0; mt < 4; ++mt) {
        f16x8 pah[2];
        #pragma unroll
        for (int kt = 0; kt < 2; ++kt)
            pah[kt] = *(const f16x8*)&Ph[w][(mt*16 + al) * 72 + kt*32 + g*8];
        f32x4 o[2] = {};
        #pragma unroll
        for (int dt = 0; dt < 2; ++dt)
            #pragma unroll
            for (int kt = 0; kt < 2; ++kt)
                o[dt] = __builtin_amdgcn_mfma_f32_16x16x32_f16(pah[kt], vhf[kt][dt], o[dt], 0, 0, 0);
        #pragma unroll
        for (int dt = 0; dt < 2; ++dt)
            #pragma unroll
            for (int rg = 0; rg < 4; ++rg) {
                float inv = __builtin_amdgcn_rcpf(sm[mt][rg]);
                float v = o[dt][rg] * inv;
                size_t off = (rbase + mt*16 + g*4 + rg) * 512 + co + dt*16 + al;
                Oout[off] = f2h(v);
            }
    }
}

// ---------------- launch ----------------
extern "C" void kernel_launch(void* const* d_in, const int* in_sizes, int n_in,
                              void* d_out, int out_size, void* d_ws, size_t ws_size,
                              hipStream_t stream)
{
    const float* x      = (const float*)d_in[0];
    const float* y      = (const float*)d_in[1];
    const float* mask   = (const float*)d_in[2];
    const float* W_q    = (const float*)d_in[3];
    const float* b_q    = (const float*)d_in[4];
    const float* W_kv   = (const float*)d_in[5];
    const float* b_kv   = (const float*)d_in[6];
    const float* W_proj = (const float*)d_in[7];
    const float* b_proj = (const float*)d_in[8];
    const float* table  = (const float*)d_in[9];

    char* ws = (char*)d_ws;
    const size_t SEG = (size_t)MROWS * 512 * sizeof(u16);   // 128 MB
    u16* Qs     = (u16*)(ws);              // aliased by O after attention
    u16* Ks     = (u16*)(ws + SEG);
    u16* Vth    = (u16*)(ws + 2 * SEG);    // V^T [win][h][d][k], fp16
    u16* wqT    = (u16*)(ws + 3 * SEG);
    u16* wkvT   = wqT  + 512 * 512;        // [1024][512] (K cols, then V cols)
    u16* wprT   = wkvT + 1024 * 512;
    float* cmb  = (float*)(wprT + 512 * 512);   // 64*16*4096*4B = 16 MB

    wt_all<<<dim3(1024, 4), 256, 0, stream>>>(W_q, W_kv, W_proj, wqT, wkvT, wprT);
    cmb_pre<<<dim3(64, 16), 256, 0, stream>>>(table, mask, cmb);

    gemm_xy<<<12288, 256, 0, stream>>>(x, y, wqT, wkvT, b_q, b_kv, Qs, Ks, Vth);
    attn64<<<dim3(2048, 4), 256, 0, stream>>>(Qs, Ks, Vth, cmb, Qs);
    gemm_proj<<<4096, 256, 0, stream>>>(Qs, wprT, b_proj, (float*)d_out);
}